// Round 2
// baseline (4229.721 us; speedup 1.0000x reference)
//
#include <hip/hip_runtime.h>
#include <math.h>

typedef unsigned short u16;

#define B_N 8
#define LSEQ 2048
#define D_INx 1024
#define D_MODELx 1024
#define D_STATEx 128
#define D_CONVx 4
#define D_INNERx 2048
#define NHEADSx 32
#define HEADDIMx 64
#define CONV_DIMx 2304
#define D_IN_PROJx 4384
#define CHUNKx 64
#define NCHUNKx 32
#define NTOK (B_N*LSEQ)   // 16384

// xbcdt workspace buffer: [NTOK][LDX] bf16, cols: 0..2047 xs (later y/yn),
// 2048..2175 B, 2176..2303 C, 2304..2335 dt_raw
#define LDX 2336
#define XB_B 2048
#define XB_C 2176
#define XB_DT 2304

// ---------- bf16 helpers (storage only; all math fp32) ----------
__device__ __forceinline__ float b2f(u16 u) {
    return __uint_as_float(((unsigned)u) << 16);
}
__device__ __forceinline__ u16 f2b(float f) {
    unsigned u = __float_as_uint(f);
    return (u16)((u + 0x7FFFu + ((u >> 16) & 1u)) >> 16);  // RNE
}

__device__ __forceinline__ float block_sum(float v) {
    __shared__ float sm[8];
    int lane = threadIdx.x & 63, wid = threadIdx.x >> 6;
    #pragma unroll
    for (int o = 32; o; o >>= 1) v += __shfl_xor(v, o);
    __syncthreads();
    if (lane == 0) sm[wid] = v;
    __syncthreads();
    float r = 0.f;
    int nw = blockDim.x >> 6;
    for (int w = 0; w < nw; ++w) r += sm[w];
    return r;
}

__device__ __forceinline__ float silu_f(float x) {
    return x / (1.f + expf(-x));
}

// ---------- GEMM: C[M,N] = A[M,K] @ W[N,K]^T (+bias); A fp32 or bf16, C fp32 or bf16 ----------
#define GBM 64
#define GBN 64
#define GBK 16
template<int ABF, int CBF>
__global__ __launch_bounds__(256) void gemm_nt(const void* __restrict__ Av,
                                               const float* __restrict__ W,
                                               const float* __restrict__ bias,
                                               void* __restrict__ Cv,
                                               int M, int N, int K, int lda, int ldc) {
    __shared__ __align__(16) float As[GBK][GBM + 4];
    __shared__ __align__(16) float Ws[GBK][GBN + 4];
    int bm = blockIdx.y * GBM;
    int bn = blockIdx.x * GBN;
    int tid = threadIdx.x;
    int tm = tid >> 4, tn = tid & 15;
    float acc[4][4] = {};
    for (int k0 = 0; k0 < K; k0 += GBK) {
        {
            int r = tid >> 2;
            int c = (tid & 3) << 2;
            if constexpr (ABF) {
                ushort4 v = *(const ushort4*)((const u16*)Av + (size_t)(bm + r) * lda + k0 + c);
                As[c + 0][r] = b2f(v.x); As[c + 1][r] = b2f(v.y);
                As[c + 2][r] = b2f(v.z); As[c + 3][r] = b2f(v.w);
            } else {
                float4 v = *(const float4*)((const float*)Av + (size_t)(bm + r) * lda + k0 + c);
                As[c + 0][r] = v.x; As[c + 1][r] = v.y; As[c + 2][r] = v.z; As[c + 3][r] = v.w;
            }
            int n = bn + r;
            float4 w = make_float4(0.f, 0.f, 0.f, 0.f);
            if (n < N) w = *(const float4*)(W + (size_t)n * K + k0 + c);
            Ws[c + 0][r] = w.x; Ws[c + 1][r] = w.y; Ws[c + 2][r] = w.z; Ws[c + 3][r] = w.w;
        }
        __syncthreads();
        #pragma unroll
        for (int k = 0; k < GBK; ++k) {
            float4 av = *(const float4*)&As[k][tm << 2];
            float4 bv = *(const float4*)&Ws[k][tn << 2];
            float a[4] = {av.x, av.y, av.z, av.w};
            float b[4] = {bv.x, bv.y, bv.z, bv.w};
            #pragma unroll
            for (int i = 0; i < 4; ++i)
                #pragma unroll
                for (int j = 0; j < 4; ++j)
                    acc[i][j] = fmaf(a[i], b[j], acc[i][j]);
        }
        __syncthreads();
    }
    #pragma unroll
    for (int i = 0; i < 4; ++i) {
        int m = bm + (tm << 2) + i;
        #pragma unroll
        for (int j = 0; j < 4; ++j) {
            int n = bn + (tn << 2) + j;
            if (n < N) {
                float v = acc[i][j];
                if (bias) v += bias[n];
                if constexpr (CBF) ((u16*)Cv)[(size_t)m * ldc + n] = f2b(v);
                else               ((float*)Cv)[(size_t)m * ldc + n] = v;
            }
        }
    }
}

// ---------- LayerNorm (in place on bf16 u), row = 1024 ----------
__global__ __launch_bounds__(256) void layernorm_k(u16* __restrict__ u,
                                                   const float* __restrict__ g,
                                                   const float* __restrict__ bt) {
    int row = blockIdx.x;
    u16* p = u + (size_t)row * D_MODELx;
    float v[4]; float s = 0.f;
    #pragma unroll
    for (int i = 0; i < 4; ++i) { v[i] = b2f(p[threadIdx.x + i * 256]); s += v[i]; }
    float mean = block_sum(s) * (1.f / D_MODELx);
    float vs = 0.f;
    #pragma unroll
    for (int i = 0; i < 4; ++i) { float d = v[i] - mean; vs += d * d; }
    float var = block_sum(vs) * (1.f / D_MODELx);
    float inv = rsqrtf(var + 1e-5f);
    #pragma unroll
    for (int i = 0; i < 4; ++i) {
        int c = threadIdx.x + i * 256;
        p[c] = f2b((v[i] - mean) * inv * g[c] + bt[c]);
    }
}

// ---------- dt (softplus) + per-chunk cumsum of A*dt ----------
__global__ void dt_acs_k(const u16* __restrict__ xb,
                         const float* __restrict__ dt_bias,
                         const float* __restrict__ A_log,
                         float* __restrict__ dtv, float* __restrict__ acs) {
    int idx = blockIdx.x * blockDim.x + threadIdx.x;
    if (idx >= B_N * NHEADSx * NCHUNKx) return;
    int c = idx % NCHUNKx;
    int h = (idx / NCHUNKx) % NHEADSx;
    int b = idx / (NCHUNKx * NHEADSx);
    float A = -expf(A_log[h]);
    float bias = dt_bias[h];
    float cum = 0.f;
    float* acp = acs + (((size_t)(b * NHEADSx + h)) * NCHUNKx + c) * CHUNKx;
    for (int l = 0; l < CHUNKx; ++l) {
        int row = b * LSEQ + c * CHUNKx + l;
        float x = b2f(xb[(size_t)row * LDX + XB_DT + h]) + bias;
        float d = (x > 20.f) ? x : log1pf(expf(x));
        dtv[(size_t)row * NHEADSx + h] = d;
        cum += A * d;
        acp[l] = cum;
    }
}

// ---------- causal depthwise conv (k=4) + SiLU, IN PLACE on xb cols [0,2304) ----------
// block = 32 channels x 8 L-segments of 256; halo read before syncthreads makes
// the in-place update race-free (each thread owns one column segment).
__global__ __launch_bounds__(256) void conv_k(u16* __restrict__ xb,
                                              const float* __restrict__ w,
                                              const float* __restrict__ bias) {
    int chl = threadIdx.x & 31, seg = threadIdx.x >> 5;
    int ch = blockIdx.x * 32 + chl;
    int b = blockIdx.y;
    float w0 = w[ch * 4 + 0], w1 = w[ch * 4 + 1], w2 = w[ch * 4 + 2], w3 = w[ch * 4 + 3];
    float bs = bias[ch];
    size_t base = ((size_t)b * LSEQ + seg * 256) * LDX + ch;
    float h0 = 0.f, h1 = 0.f, h2 = 0.f;
    if (seg) {
        h0 = b2f(xb[base - 3 * (size_t)LDX]);
        h1 = b2f(xb[base - 2 * (size_t)LDX]);
        h2 = b2f(xb[base - 1 * (size_t)LDX]);
    }
    __syncthreads();
    for (int i = 0; i < 256; ++i) {
        float xl = b2f(xb[base + (size_t)i * LDX]);
        float o = fmaf(w3, xl, fmaf(w2, h2, fmaf(w1, h1, fmaf(w0, h0, bs))));
        xb[base + (size_t)i * LDX] = f2b(silu_f(o));
        h0 = h1; h1 = h2; h2 = xl;
    }
}

// ---------- G[b][c][l][s] = dot(Cm[l], Bm[s]) ----------
__global__ __launch_bounds__(256) void gscore_k(const u16* __restrict__ xb,
                                                float* __restrict__ G) {
    int bc = blockIdx.x;
    int b = bc / NCHUNKx, c = bc % NCHUNKx;
    __shared__ __align__(16) float Ct[D_STATEx][CHUNKx + 1];
    __shared__ __align__(16) float Bt[D_STATEx][CHUNKx + 1];
    int tid = threadIdx.x;
    for (int t = tid; t < 64 * 32; t += 256) {
        int l = t >> 5; int nq = (t & 31) << 2;
        const u16* base = xb + (size_t)(b * LSEQ + c * CHUNKx + l) * LDX + XB_B;
        ushort4 bb = *(const ushort4*)(base + nq);
        ushort4 cc = *(const ushort4*)(base + 128 + nq);
        Bt[nq + 0][l] = b2f(bb.x); Bt[nq + 1][l] = b2f(bb.y);
        Bt[nq + 2][l] = b2f(bb.z); Bt[nq + 3][l] = b2f(bb.w);
        Ct[nq + 0][l] = b2f(cc.x); Ct[nq + 1][l] = b2f(cc.y);
        Ct[nq + 2][l] = b2f(cc.z); Ct[nq + 3][l] = b2f(cc.w);
    }
    __syncthreads();
    int lg = tid >> 4, sg = tid & 15;
    float acc[4][4] = {};
    for (int n = 0; n < D_STATEx; ++n) {
        float a[4], bb[4];
        #pragma unroll
        for (int i = 0; i < 4; ++i) a[i] = Ct[n][(lg << 2) + i];
        #pragma unroll
        for (int j = 0; j < 4; ++j) bb[j] = Bt[n][(sg << 2) + j];
        #pragma unroll
        for (int i = 0; i < 4; ++i)
            #pragma unroll
            for (int j = 0; j < 4; ++j) acc[i][j] = fmaf(a[i], bb[j], acc[i][j]);
    }
    float* g = G + (size_t)bc * CHUNKx * CHUNKx;
    #pragma unroll
    for (int i = 0; i < 4; ++i)
        #pragma unroll
        for (int j = 0; j < 4; ++j)
            g[((lg << 2) + i) * CHUNKx + (sg << 2) + j] = acc[i][j];
}

// ---------- per-chunk states: states[c][h][p][n] (fp32) ----------
__global__ __launch_bounds__(256) void states_k(const u16* __restrict__ xb,
                                                const float* __restrict__ dtv,
                                                const float* __restrict__ acs,
                                                float* __restrict__ states, int b) {
    int c = blockIdx.x, h = blockIdx.y;
    __shared__ __align__(16) float xd[CHUNKx][HEADDIMx + 4];
    __shared__ __align__(16) float Bs[CHUNKx][D_STATEx + 4];
    __shared__ float dec[CHUNKx];
    int tid = threadIdx.x;
    const float* acp = acs + (((size_t)(b * NHEADSx + h)) * NCHUNKx + c) * CHUNKx;
    if (tid < CHUNKx) dec[tid] = expf(acp[CHUNKx - 1] - acp[tid]);
    __syncthreads();
    for (int t = tid; t < 64 * 16; t += 256) {
        int l = t >> 4; int pq = (t & 15) << 2;
        int row = b * LSEQ + c * CHUNKx + l;
        ushort4 v = *(const ushort4*)(xb + (size_t)row * LDX + h * HEADDIMx + pq);
        float s = dtv[(size_t)row * NHEADSx + h] * dec[l];
        xd[l][pq + 0] = b2f(v.x) * s; xd[l][pq + 1] = b2f(v.y) * s;
        xd[l][pq + 2] = b2f(v.z) * s; xd[l][pq + 3] = b2f(v.w) * s;
    }
    for (int t = tid; t < 64 * 32; t += 256) {
        int l = t >> 5; int nq = (t & 31) << 2;
        int row = b * LSEQ + c * CHUNKx + l;
        ushort4 v = *(const ushort4*)(xb + (size_t)row * LDX + XB_B + nq);
        Bs[l][nq + 0] = b2f(v.x); Bs[l][nq + 1] = b2f(v.y);
        Bs[l][nq + 2] = b2f(v.z); Bs[l][nq + 3] = b2f(v.w);
    }
    __syncthreads();
    int pg = tid >> 4, ng = tid & 15;  // p: 4, n: 8
    float acc[4][8] = {};
    for (int l = 0; l < CHUNKx; ++l) {
        float4 a4 = *(const float4*)&xd[l][pg << 2];
        float4 b0 = *(const float4*)&Bs[l][ng << 3];
        float4 b1 = *(const float4*)&Bs[l][(ng << 3) + 4];
        float a[4] = {a4.x, a4.y, a4.z, a4.w};
        float bb[8] = {b0.x, b0.y, b0.z, b0.w, b1.x, b1.y, b1.z, b1.w};
        #pragma unroll
        for (int i = 0; i < 4; ++i)
            #pragma unroll
            for (int j = 0; j < 8; ++j) acc[i][j] = fmaf(a[i], bb[j], acc[i][j]);
    }
    float* sp = states + ((size_t)(c * NHEADSx + h)) * HEADDIMx * D_STATEx;
    #pragma unroll
    for (int i = 0; i < 4; ++i) {
        int p = (pg << 2) + i;
        #pragma unroll
        for (int j = 0; j < 8; ++j)
            sp[(size_t)p * D_STATEx + (ng << 3) + j] = acc[i][j];
    }
}

// ---------- inter-chunk scan (in place) ----------
__global__ void scan_k(const float* __restrict__ acs, float* __restrict__ states, int b) {
    int h = blockIdx.y;
    int pn = blockIdx.x * 256 + threadIdx.x;
    const float* acp = acs + ((size_t)(b * NHEADSx + h)) * NCHUNKx * CHUNKx;
    float carry = 0.f;
    for (int c = 0; c < NCHUNKx; ++c) {
        size_t idx = ((size_t)(c * NHEADSx + h)) * HEADDIMx * D_STATEx + pn;
        float s = states[idx];
        states[idx] = carry;
        carry = fmaf(carry, expf(acp[c * CHUNKx + CHUNKx - 1]), s);
    }
}

// ---------- Y = Y_diag + Y_off + D*xs, written bf16 over the xs columns ----------
__global__ __launch_bounds__(256) void yout_k(u16* __restrict__ xb,
                                              const float* __restrict__ dtv,
                                              const float* __restrict__ acs,
                                              const float* __restrict__ G,
                                              const float* __restrict__ states,
                                              const float* __restrict__ Dp, int b) {
    int c = blockIdx.x, h = blockIdx.y;
    __shared__ __align__(16) float G2[CHUNKx][CHUNKx + 4];
    __shared__ __align__(16) float xd[CHUNKx][HEADDIMx + 4];
    __shared__ __align__(16) float Ct[D_STATEx][CHUNKx + 4];
    __shared__ __align__(16) float St[D_STATEx][HEADDIMx + 4];
    __shared__ float ea[CHUNKx];
    __shared__ float acss[CHUNKx];
    int tid = threadIdx.x;
    const float* acp = acs + (((size_t)(b * NHEADSx + h)) * NCHUNKx + c) * CHUNKx;
    if (tid < CHUNKx) { float v = acp[tid]; acss[tid] = v; ea[tid] = expf(v); }
    __syncthreads();
    const float* g = G + ((size_t)(b * NCHUNKx + c)) * CHUNKx * CHUNKx;
    for (int t = tid; t < CHUNKx * CHUNKx; t += 256) {
        int l = t >> 6, s = t & 63;
        float v = 0.f;
        if (s <= l) v = g[t] * expf(acss[l] - acss[s]);
        G2[l][s] = v;
    }
    for (int t = tid; t < 64 * 16; t += 256) {
        int l = t >> 4; int pq = (t & 15) << 2;
        int row = b * LSEQ + c * CHUNKx + l;
        ushort4 v = *(const ushort4*)(xb + (size_t)row * LDX + h * HEADDIMx + pq);
        float d = dtv[(size_t)row * NHEADSx + h];
        xd[l][pq + 0] = b2f(v.x) * d; xd[l][pq + 1] = b2f(v.y) * d;
        xd[l][pq + 2] = b2f(v.z) * d; xd[l][pq + 3] = b2f(v.w) * d;
    }
    for (int t = tid; t < 64 * 32; t += 256) {
        int l = t >> 5; int nq = (t & 31) << 2;
        int row = b * LSEQ + c * CHUNKx + l;
        ushort4 v = *(const ushort4*)(xb + (size_t)row * LDX + XB_C + nq);
        Ct[nq + 0][l] = b2f(v.x); Ct[nq + 1][l] = b2f(v.y);
        Ct[nq + 2][l] = b2f(v.z); Ct[nq + 3][l] = b2f(v.w);
    }
    const float* sp = states + ((size_t)(c * NHEADSx + h)) * HEADDIMx * D_STATEx;
    for (int t = tid; t < 64 * 32; t += 256) {
        int p = t >> 5; int nq = (t & 31) << 2;
        float4 v = *(const float4*)(sp + (size_t)p * D_STATEx + nq);
        St[nq + 0][p] = v.x; St[nq + 1][p] = v.y; St[nq + 2][p] = v.z; St[nq + 3][p] = v.w;
    }
    __syncthreads();
    int lg = tid >> 4, pg = tid & 15;
    float acc[4][4] = {};
    for (int s = 0; s < CHUNKx; ++s) {
        float4 bv = *(const float4*)&xd[s][pg << 2];
        float bb[4] = {bv.x, bv.y, bv.z, bv.w};
        float a[4];
        #pragma unroll
        for (int i = 0; i < 4; ++i) a[i] = G2[(lg << 2) + i][s];
        #pragma unroll
        for (int i = 0; i < 4; ++i)
            #pragma unroll
            for (int j = 0; j < 4; ++j) acc[i][j] = fmaf(a[i], bb[j], acc[i][j]);
    }
    float acc2[4][4] = {};
    for (int n = 0; n < D_STATEx; ++n) {
        float4 bv = *(const float4*)&St[n][pg << 2];
        float bb[4] = {bv.x, bv.y, bv.z, bv.w};
        float a[4];
        #pragma unroll
        for (int i = 0; i < 4; ++i) a[i] = Ct[n][(lg << 2) + i];
        #pragma unroll
        for (int i = 0; i < 4; ++i)
            #pragma unroll
            for (int j = 0; j < 4; ++j) acc2[i][j] = fmaf(a[i], bb[j], acc2[i][j]);
    }
    float Dh = Dp[h];
    #pragma unroll
    for (int i = 0; i < 4; ++i) {
        int l = (lg << 2) + i;
        int row = b * LSEQ + c * CHUNKx + l;
        float eA = ea[l];
        u16* yrow = xb + (size_t)row * LDX + h * HEADDIMx;
        #pragma unroll
        for (int j = 0; j < 4; ++j) {
            int p = (pg << 2) + j;
            float xsv = b2f(yrow[p]);   // own element: read-then-write is safe
            yrow[p] = f2b(acc[i][j] + eA * acc2[i][j] + Dh * xsv);
        }
    }
}

// ---------- gated RMSNorm: yn = (y*silu(z)) * rsqrt(mean(y^2)+eps) * w, in place over y ----------
__global__ __launch_bounds__(256) void rmsgate_k(u16* __restrict__ xb,
                                                 const u16* __restrict__ zb,
                                                 const float* __restrict__ w) {
    int row = blockIdx.x;
    const u16* zp = zb + (size_t)row * D_INNERx;
    u16* yp = xb + (size_t)row * LDX;
    float vals[8];
    float ss = 0.f;
    #pragma unroll
    for (int i = 0; i < 8; ++i) {
        int c = threadIdx.x + i * 256;
        float z = b2f(zp[c]);
        float y = b2f(yp[c]) * silu_f(z);
        vals[i] = y; ss += y * y;
    }
    float tot = block_sum(ss);
    float scale = rsqrtf(tot * (1.f / D_INNERx) + 1e-5f);
    #pragma unroll
    for (int i = 0; i < 8; ++i) {
        int c = threadIdx.x + i * 256;
        yp[c] = f2b(vals[i] * scale * w[c]);
    }
}

// ---------- hidden = out[:, -1, :] ----------
__global__ void hidden_k(float* __restrict__ out) {
    int i = blockIdx.x * blockDim.x + threadIdx.x;
    int b = i >> 10, d = i & 1023;
    out[(size_t)NTOK * D_MODELx + i] = out[((size_t)(b * LSEQ + LSEQ - 1)) * D_MODELx + d];
}

extern "C" void kernel_launch(void* const* d_in, const int* in_sizes, int n_in,
                              void* d_out, int out_size, void* d_ws, size_t ws_size,
                              hipStream_t stream) {
    const float* x       = (const float*)d_in[0];
    const float* Wi      = (const float*)d_in[1];
    const float* bi      = (const float*)d_in[2];
    const float* ln_g    = (const float*)d_in[3];
    const float* ln_b    = (const float*)d_in[4];
    const float* Win     = (const float*)d_in[5];
    const float* conv_w  = (const float*)d_in[6];
    const float* conv_b  = (const float*)d_in[7];
    const float* dt_bias = (const float*)d_in[8];
    const float* A_log   = (const float*)d_in[9];
    const float* Dv      = (const float*)d_in[10];
    const float* rms_w   = (const float*)d_in[11];
    const float* Wout    = (const float*)d_in[12];
    float* out = (float*)d_out;

    // workspace layout (bytes): xbcdt 76,546,048 | u/states 33,554,432 | G 4,194,304
    //                           | acs 2,097,152 | dtv 2,097,152  = 118,489,088 total
    if (ws_size < 118489088ull) return;  // diagnostic guard: absmax-fail => ws too small
    u16* xb  = (u16*)d_ws;                                   // [NTOK][LDX] bf16
    u16* ub  = xb + (size_t)NTOK * LDX;                      // [NTOK][1024] bf16 (u)
    float* states = (float*)ub;                              // overlay: 32*32*64*128 fp32 (u dead post-GEMM2)
    float* G   = (float*)(ub + (size_t)NTOK * D_MODELx);     // 8*32*64*64
    float* acs = G + (size_t)B_N * NCHUNKx * CHUNKx * CHUNKx;   // 8*32*32*64
    float* dtv = acs + (size_t)B_N * NHEADSx * NCHUNKx * CHUNKx; // 16384*32
    u16* zb  = (u16*)d_out;                                  // z: [NTOK][2048] bf16, dead before GEMM3

    // 1. u = x @ Wi^T + bi  (fp32 in, bf16 out)
    gemm_nt<0, 1><<<dim3(D_MODELx / GBN, NTOK / GBM), 256, 0, stream>>>(
        x, Wi, bi, ub, NTOK, D_MODELx, D_INx, D_INx, D_MODELx);
    // 2. LayerNorm in place (bf16)
    layernorm_k<<<NTOK, 256, 0, stream>>>(ub, ln_g, ln_b);
    // 3a. z = u @ Win[0:2048]^T  -> d_out (bf16)
    gemm_nt<1, 1><<<dim3(D_INNERx / GBN, NTOK / GBM), 256, 0, stream>>>(
        ub, Win, nullptr, zb, NTOK, D_INNERx, D_MODELx, D_MODELx, D_INNERx);
    // 3b. xBCdt = u @ Win[2048:4384]^T -> xb (bf16)
    gemm_nt<1, 1><<<dim3((LDX + GBN - 1) / GBN, NTOK / GBM), 256, 0, stream>>>(
        ub, Win + (size_t)D_INNERx * D_MODELx, nullptr, xb, NTOK, LDX, D_MODELx, D_MODELx, LDX);
    // 4. dt + per-chunk cumsum of A*dt
    dt_acs_k<<<(B_N * NHEADSx * NCHUNKx + 255) / 256, 256, 0, stream>>>(
        xb, dt_bias, A_log, dtv, acs);
    // 5. conv + silu, in place on xb cols [0,2304)
    conv_k<<<dim3(CONV_DIMx / 32, B_N), 256, 0, stream>>>(xb, conv_w, conv_b);
    // 6. G scores
    gscore_k<<<B_N * NCHUNKx, 256, 0, stream>>>(xb, G);
    // 7. SSD per batch (states overlays dead u)
    for (int b = 0; b < B_N; ++b) {
        states_k<<<dim3(NCHUNKx, NHEADSx), 256, 0, stream>>>(xb, dtv, acs, states, b);
        scan_k<<<dim3(HEADDIMx * D_STATEx / 256, NHEADSx), 256, 0, stream>>>(acs, states, b);
        yout_k<<<dim3(NCHUNKx, NHEADSx), 256, 0, stream>>>(xb, dtv, acs, G, states, Dv, b);
    }
    // 8. gated RMSNorm in place over y (xb cols [0,2048))
    rmsgate_k<<<NTOK, 256, 0, stream>>>(xb, zb, rms_w);
    // 9. out = yn @ Wout^T (bf16 A strided lda=LDX, fp32 out; overwrites z region)
    gemm_nt<1, 0><<<dim3(D_MODELx / GBN, NTOK / GBM), 256, 0, stream>>>(
        xb, Wout, nullptr, out, NTOK, D_MODELx, D_INNERx, LDX, D_MODELx);
    // 10. hidden
    hidden_k<<<(B_N * D_MODELx) / 256, 256, 0, stream>>>(out);
}

// Round 3
// 1369.746 us; speedup vs baseline: 3.0880x; 3.0880x over previous
//
#include <hip/hip_runtime.h>
#include <math.h>

typedef unsigned short u16;
typedef __attribute__((ext_vector_type(8))) short bf16x8;
typedef __attribute__((ext_vector_type(4))) float f32x4;

#define B_N 8
#define LSEQ 2048
#define D_INx 1024
#define D_MODELx 1024
#define D_STATEx 128
#define D_CONVx 4
#define D_INNERx 2048
#define NHEADSx 32
#define HEADDIMx 64
#define CONV_DIMx 2304
#define D_IN_PROJx 4384
#define CHUNKx 64
#define NCHUNKx 32
#define NTOK (B_N*LSEQ)   // 16384

#define LDX 2336
#define XB_B 2048
#define XB_C 2176
#define XB_DT 2304

// ---------- bf16 helpers (storage only; math fp32) ----------
__device__ __forceinline__ float b2f(u16 u) {
    return __uint_as_float(((unsigned)u) << 16);
}
__device__ __forceinline__ u16 f2b(float f) {
    unsigned u = __float_as_uint(f);
    return (u16)((u + 0x7FFFu + ((u >> 16) & 1u)) >> 16);  // RNE
}

__device__ __forceinline__ float block_sum(float v) {
    __shared__ float sm[8];
    int lane = threadIdx.x & 63, wid = threadIdx.x >> 6;
    #pragma unroll
    for (int o = 32; o; o >>= 1) v += __shfl_xor(v, o);
    __syncthreads();
    if (lane == 0) sm[wid] = v;
    __syncthreads();
    float r = 0.f;
    int nw = blockDim.x >> 6;
    for (int w = 0; w < nw; ++w) r += sm[w];
    return r;
}

__device__ __forceinline__ float silu_f(float x) {
    return x / (1.f + expf(-x));
}

// ---------- fp32 -> bf16 conversion (vectorized) ----------
__global__ __launch_bounds__(256) void cvt_f2b_k(const float* __restrict__ in,
                                                 u16* __restrict__ out, int n4) {
    int i = blockIdx.x * 256 + threadIdx.x;
    if (i >= n4) return;
    float4 v = ((const float4*)in)[i];
    ushort4 o;
    o.x = f2b(v.x); o.y = f2b(v.y); o.z = f2b(v.z); o.w = f2b(v.w);
    ((ushort4*)out)[i] = o;
}

// ---------- bf16 MFMA GEMM: C[M,N] = A[M,K] @ W[N,K]^T (+bias) ----------
// m97 structure: 128x128 tile, BK=32, 4 waves (2x2), global_load_lds width 16,
// 2-barrier K-loop. M%128==0, K%32==0; N ragged handled by predicated C-write
// (W buffer must be row-padded to next multiple of 128 rows).
template<int CBF>
__global__ __launch_bounds__(256) void gemm_mfma(const u16* __restrict__ A,
                                                 const u16* __restrict__ W,
                                                 const float* __restrict__ bias,
                                                 void* __restrict__ Cv,
                                                 int M, int N, int K, int lda, int ldc) {
    __shared__ u16 As[128 * 32];
    __shared__ u16 Bs[128 * 32];

    // XCD-aware swizzle (grids here always have nwg % 8 == 0)
    int nwgx = gridDim.x;
    int nwg = nwgx * gridDim.y;
    int bid = blockIdx.y * nwgx + blockIdx.x;
    int cpx = nwg >> 3;
    bid = (bid & 7) * cpx + (bid >> 3);
    int bm = (bid / nwgx) * 128;
    int bn = (bid % nwgx) * 128;

    int tid = threadIdx.x, wid = tid >> 6, lane = tid & 63;
    int lr = lane & 15, lk = (lane >> 4) << 3;
    int wr = (wid >> 1) << 6, wc = (wid & 1) << 6;

    // staging pointers: wave w owns chunks 4w..4w+3 (0..7 = A, 8..15 = B)
    const u16* srcp[4];
    u16* ldsp[4];
    #pragma unroll
    for (int cc = 0; cc < 4; ++cc) {
        int ch = wid * 4 + cc;
        int r = lane >> 2, col8 = (lane & 3) << 3;
        if (ch < 8) {
            srcp[cc] = A + (size_t)(bm + ch * 16 + r) * lda + col8;
            ldsp[cc] = &As[ch * 512];
        } else {
            srcp[cc] = W + (size_t)(bn + (ch - 8) * 16 + r) * K + col8;
            ldsp[cc] = &Bs[(ch - 8) * 512];
        }
    }

    f32x4 acc[4][4];
    #pragma unroll
    for (int m = 0; m < 4; ++m)
        #pragma unroll
        for (int n = 0; n < 4; ++n)
            acc[m][n] = (f32x4){0.f, 0.f, 0.f, 0.f};

    for (int k0 = 0; k0 < K; k0 += 32) {
        #pragma unroll
        for (int cc = 0; cc < 4; ++cc)
            __builtin_amdgcn_global_load_lds(
                (const __attribute__((address_space(1))) void*)(srcp[cc] + k0),
                (__attribute__((address_space(3))) void*)ldsp[cc], 16, 0, 0);
        __syncthreads();
        bf16x8 af[4], bfr[4];
        #pragma unroll
        for (int m = 0; m < 4; ++m)
            af[m] = *(bf16x8*)&As[(wr + m * 16 + lr) * 32 + lk];
        #pragma unroll
        for (int n = 0; n < 4; ++n)
            bfr[n] = *(bf16x8*)&Bs[(wc + n * 16 + lr) * 32 + lk];
        #pragma unroll
        for (int m = 0; m < 4; ++m)
            #pragma unroll
            for (int n = 0; n < 4; ++n)
                acc[m][n] = __builtin_amdgcn_mfma_f32_16x16x32_bf16(af[m], bfr[n], acc[m][n], 0, 0, 0);
        __syncthreads();
    }

    int crow = bm + wr + ((lane >> 4) << 2);
    int ccol = bn + wc + (lane & 15);
    #pragma unroll
    for (int n = 0; n < 4; ++n) {
        int col = ccol + n * 16;
        if (col < N) {
            float bv = bias ? bias[col] : 0.f;
            #pragma unroll
            for (int m = 0; m < 4; ++m) {
                #pragma unroll
                for (int j = 0; j < 4; ++j) {
                    int row = crow + m * 16 + j;
                    float v = acc[m][n][j] + bv;
                    if constexpr (CBF) ((u16*)Cv)[(size_t)row * ldc + col] = f2b(v);
                    else               ((float*)Cv)[(size_t)row * ldc + col] = v;
                }
            }
        }
    }
}

// ---------- LayerNorm (in place on bf16 u), row = 1024 ----------
__global__ __launch_bounds__(256) void layernorm_k(u16* __restrict__ u,
                                                   const float* __restrict__ g,
                                                   const float* __restrict__ bt) {
    int row = blockIdx.x;
    u16* p = u + (size_t)row * D_MODELx;
    float v[4]; float s = 0.f;
    #pragma unroll
    for (int i = 0; i < 4; ++i) { v[i] = b2f(p[threadIdx.x + i * 256]); s += v[i]; }
    float mean = block_sum(s) * (1.f / D_MODELx);
    float vs = 0.f;
    #pragma unroll
    for (int i = 0; i < 4; ++i) { float d = v[i] - mean; vs += d * d; }
    float var = block_sum(vs) * (1.f / D_MODELx);
    float inv = rsqrtf(var + 1e-5f);
    #pragma unroll
    for (int i = 0; i < 4; ++i) {
        int c = threadIdx.x + i * 256;
        p[c] = f2b((v[i] - mean) * inv * g[c] + bt[c]);
    }
}

// ---------- dt (softplus) + per-chunk cumsum of A*dt ----------
__global__ void dt_acs_k(const u16* __restrict__ xb,
                         const float* __restrict__ dt_bias,
                         const float* __restrict__ A_log,
                         float* __restrict__ dtv, float* __restrict__ acs) {
    int idx = blockIdx.x * blockDim.x + threadIdx.x;
    if (idx >= B_N * NHEADSx * NCHUNKx) return;
    int c = idx % NCHUNKx;
    int h = (idx / NCHUNKx) % NHEADSx;
    int b = idx / (NCHUNKx * NHEADSx);
    float A = -expf(A_log[h]);
    float bias = dt_bias[h];
    float cum = 0.f;
    float* acp = acs + (((size_t)(b * NHEADSx + h)) * NCHUNKx + c) * CHUNKx;
    for (int l = 0; l < CHUNKx; ++l) {
        int row = b * LSEQ + c * CHUNKx + l;
        float x = b2f(xb[(size_t)row * LDX + XB_DT + h]) + bias;
        float d = (x > 20.f) ? x : log1pf(expf(x));
        dtv[(size_t)row * NHEADSx + h] = d;
        cum += A * d;
        acp[l] = cum;
    }
}

// ---------- causal depthwise conv (k=4) + SiLU, IN PLACE on xb cols [0,2304) ----------
__global__ __launch_bounds__(256) void conv_k(u16* __restrict__ xb,
                                              const float* __restrict__ w,
                                              const float* __restrict__ bias) {
    int chl = threadIdx.x & 31, seg = threadIdx.x >> 5;
    int ch = blockIdx.x * 32 + chl;
    int b = blockIdx.y;
    float w0 = w[ch * 4 + 0], w1 = w[ch * 4 + 1], w2 = w[ch * 4 + 2], w3 = w[ch * 4 + 3];
    float bs = bias[ch];
    size_t base = ((size_t)b * LSEQ + seg * 256) * LDX + ch;
    float h0 = 0.f, h1 = 0.f, h2 = 0.f;
    if (seg) {
        h0 = b2f(xb[base - 3 * (size_t)LDX]);
        h1 = b2f(xb[base - 2 * (size_t)LDX]);
        h2 = b2f(xb[base - 1 * (size_t)LDX]);
    }
    __syncthreads();
    for (int i = 0; i < 256; ++i) {
        float xl = b2f(xb[base + (size_t)i * LDX]);
        float o = fmaf(w3, xl, fmaf(w2, h2, fmaf(w1, h1, fmaf(w0, h0, bs))));
        xb[base + (size_t)i * LDX] = f2b(silu_f(o));
        h0 = h1; h1 = h2; h2 = xl;
    }
}

// ---------- G[b][c][l][s] = dot(Cm[l], Bm[s]) ----------
__global__ __launch_bounds__(256) void gscore_k(const u16* __restrict__ xb,
                                                float* __restrict__ G) {
    int bc = blockIdx.x;
    int b = bc / NCHUNKx, c = bc % NCHUNKx;
    __shared__ __align__(16) float Ct[D_STATEx][CHUNKx + 1];
    __shared__ __align__(16) float Bt[D_STATEx][CHUNKx + 1];
    int tid = threadIdx.x;
    for (int t = tid; t < 64 * 32; t += 256) {
        int l = t >> 5; int nq = (t & 31) << 2;
        const u16* base = xb + (size_t)(b * LSEQ + c * CHUNKx + l) * LDX + XB_B;
        ushort4 bb = *(const ushort4*)(base + nq);
        ushort4 cc = *(const ushort4*)(base + 128 + nq);
        Bt[nq + 0][l] = b2f(bb.x); Bt[nq + 1][l] = b2f(bb.y);
        Bt[nq + 2][l] = b2f(bb.z); Bt[nq + 3][l] = b2f(bb.w);
        Ct[nq + 0][l] = b2f(cc.x); Ct[nq + 1][l] = b2f(cc.y);
        Ct[nq + 2][l] = b2f(cc.z); Ct[nq + 3][l] = b2f(cc.w);
    }
    __syncthreads();
    int lg = tid >> 4, sg = tid & 15;
    float acc[4][4] = {};
    for (int n = 0; n < D_STATEx; ++n) {
        float a[4], bb[4];
        #pragma unroll
        for (int i = 0; i < 4; ++i) a[i] = Ct[n][(lg << 2) + i];
        #pragma unroll
        for (int j = 0; j < 4; ++j) bb[j] = Bt[n][(sg << 2) + j];
        #pragma unroll
        for (int i = 0; i < 4; ++i)
            #pragma unroll
            for (int j = 0; j < 4; ++j) acc[i][j] = fmaf(a[i], bb[j], acc[i][j]);
    }
    float* g = G + (size_t)bc * CHUNKx * CHUNKx;
    #pragma unroll
    for (int i = 0; i < 4; ++i)
        #pragma unroll
        for (int j = 0; j < 4; ++j)
            g[((lg << 2) + i) * CHUNKx + (sg << 2) + j] = acc[i][j];
}

// ---------- per-chunk states: states[c][h][p][n] (fp32) ----------
__global__ __launch_bounds__(256) void states_k(const u16* __restrict__ xb,
                                                const float* __restrict__ dtv,
                                                const float* __restrict__ acs,
                                                float* __restrict__ states, int b) {
    int c = blockIdx.x, h = blockIdx.y;
    __shared__ __align__(16) float xd[CHUNKx][HEADDIMx + 4];
    __shared__ __align__(16) float Bs[CHUNKx][D_STATEx + 4];
    __shared__ float dec[CHUNKx];
    int tid = threadIdx.x;
    const float* acp = acs + (((size_t)(b * NHEADSx + h)) * NCHUNKx + c) * CHUNKx;
    if (tid < CHUNKx) dec[tid] = expf(acp[CHUNKx - 1] - acp[tid]);
    __syncthreads();
    for (int t = tid; t < 64 * 16; t += 256) {
        int l = t >> 4; int pq = (t & 15) << 2;
        int row = b * LSEQ + c * CHUNKx + l;
        ushort4 v = *(const ushort4*)(xb + (size_t)row * LDX + h * HEADDIMx + pq);
        float s = dtv[(size_t)row * NHEADSx + h] * dec[l];
        xd[l][pq + 0] = b2f(v.x) * s; xd[l][pq + 1] = b2f(v.y) * s;
        xd[l][pq + 2] = b2f(v.z) * s; xd[l][pq + 3] = b2f(v.w) * s;
    }
    for (int t = tid; t < 64 * 32; t += 256) {
        int l = t >> 5; int nq = (t & 31) << 2;
        int row = b * LSEQ + c * CHUNKx + l;
        ushort4 v = *(const ushort4*)(xb + (size_t)row * LDX + XB_B + nq);
        Bs[l][nq + 0] = b2f(v.x); Bs[l][nq + 1] = b2f(v.y);
        Bs[l][nq + 2] = b2f(v.z); Bs[l][nq + 3] = b2f(v.w);
    }
    __syncthreads();
    int pg = tid >> 4, ng = tid & 15;  // p: 4, n: 8
    float acc[4][8] = {};
    for (int l = 0; l < CHUNKx; ++l) {
        float4 a4 = *(const float4*)&xd[l][pg << 2];
        float4 b0 = *(const float4*)&Bs[l][ng << 3];
        float4 b1 = *(const float4*)&Bs[l][(ng << 3) + 4];
        float a[4] = {a4.x, a4.y, a4.z, a4.w};
        float bb[8] = {b0.x, b0.y, b0.z, b0.w, b1.x, b1.y, b1.z, b1.w};
        #pragma unroll
        for (int i = 0; i < 4; ++i)
            #pragma unroll
            for (int j = 0; j < 8; ++j) acc[i][j] = fmaf(a[i], bb[j], acc[i][j]);
    }
    float* sp = states + ((size_t)(c * NHEADSx + h)) * HEADDIMx * D_STATEx;
    #pragma unroll
    for (int i = 0; i < 4; ++i) {
        int p = (pg << 2) + i;
        #pragma unroll
        for (int j = 0; j < 8; ++j)
            sp[(size_t)p * D_STATEx + (ng << 3) + j] = acc[i][j];
    }
}

// ---------- inter-chunk scan (in place) ----------
__global__ void scan_k(const float* __restrict__ acs, float* __restrict__ states, int b) {
    int h = blockIdx.y;
    int pn = blockIdx.x * 256 + threadIdx.x;
    const float* acp = acs + ((size_t)(b * NHEADSx + h)) * NCHUNKx * CHUNKx;
    float carry = 0.f;
    for (int c = 0; c < NCHUNKx; ++c) {
        size_t idx = ((size_t)(c * NHEADSx + h)) * HEADDIMx * D_STATEx + pn;
        float s = states[idx];
        states[idx] = carry;
        carry = fmaf(carry, expf(acp[c * CHUNKx + CHUNKx - 1]), s);
    }
}

// ---------- Y = Y_diag + Y_off + D*xs, written bf16 over the xs columns ----------
__global__ __launch_bounds__(256) void yout_k(u16* __restrict__ xb,
                                              const float* __restrict__ dtv,
                                              const float* __restrict__ acs,
                                              const float* __restrict__ G,
                                              const float* __restrict__ states,
                                              const float* __restrict__ Dp, int b) {
    int c = blockIdx.x, h = blockIdx.y;
    __shared__ __align__(16) float G2[CHUNKx][CHUNKx + 4];
    __shared__ __align__(16) float xd[CHUNKx][HEADDIMx + 4];
    __shared__ __align__(16) float Ct[D_STATEx][CHUNKx + 4];
    __shared__ __align__(16) float St[D_STATEx][HEADDIMx + 4];
    __shared__ float ea[CHUNKx];
    __shared__ float acss[CHUNKx];
    int tid = threadIdx.x;
    const float* acp = acs + (((size_t)(b * NHEADSx + h)) * NCHUNKx + c) * CHUNKx;
    if (tid < CHUNKx) { float v = acp[tid]; acss[tid] = v; ea[tid] = expf(v); }
    __syncthreads();
    const float* g = G + ((size_t)(b * NCHUNKx + c)) * CHUNKx * CHUNKx;
    for (int t = tid; t < CHUNKx * CHUNKx; t += 256) {
        int l = t >> 6, s = t & 63;
        float v = 0.f;
        if (s <= l) v = g[t] * expf(acss[l] - acss[s]);
        G2[l][s] = v;
    }
    for (int t = tid; t < 64 * 16; t += 256) {
        int l = t >> 4; int pq = (t & 15) << 2;
        int row = b * LSEQ + c * CHUNKx + l;
        ushort4 v = *(const ushort4*)(xb + (size_t)row * LDX + h * HEADDIMx + pq);
        float d = dtv[(size_t)row * NHEADSx + h];
        xd[l][pq + 0] = b2f(v.x) * d; xd[l][pq + 1] = b2f(v.y) * d;
        xd[l][pq + 2] = b2f(v.z) * d; xd[l][pq + 3] = b2f(v.w) * d;
    }
    for (int t = tid; t < 64 * 32; t += 256) {
        int l = t >> 5; int nq = (t & 31) << 2;
        int row = b * LSEQ + c * CHUNKx + l;
        ushort4 v = *(const ushort4*)(xb + (size_t)row * LDX + XB_C + nq);
        Ct[nq + 0][l] = b2f(v.x); Ct[nq + 1][l] = b2f(v.y);
        Ct[nq + 2][l] = b2f(v.z); Ct[nq + 3][l] = b2f(v.w);
    }
    const float* sp = states + ((size_t)(c * NHEADSx + h)) * HEADDIMx * D_STATEx;
    for (int t = tid; t < 64 * 32; t += 256) {
        int p = t >> 5; int nq = (t & 31) << 2;
        float4 v = *(const float4*)(sp + (size_t)p * D_STATEx + nq);
        St[nq + 0][p] = v.x; St[nq + 1][p] = v.y; St[nq + 2][p] = v.z; St[nq + 3][p] = v.w;
    }
    __syncthreads();
    int lg = tid >> 4, pg = tid & 15;
    float acc[4][4] = {};
    for (int s = 0; s < CHUNKx; ++s) {
        float4 bv = *(const float4*)&xd[s][pg << 2];
        float bb[4] = {bv.x, bv.y, bv.z, bv.w};
        float a[4];
        #pragma unroll
        for (int i = 0; i < 4; ++i) a[i] = G2[(lg << 2) + i][s];
        #pragma unroll
        for (int i = 0; i < 4; ++i)
            #pragma unroll
            for (int j = 0; j < 4; ++j) acc[i][j] = fmaf(a[i], bb[j], acc[i][j]);
    }
    float acc2[4][4] = {};
    for (int n = 0; n < D_STATEx; ++n) {
        float4 bv = *(const float4*)&St[n][pg << 2];
        float bb[4] = {bv.x, bv.y, bv.z, bv.w};
        float a[4];
        #pragma unroll
        for (int i = 0; i < 4; ++i) a[i] = Ct[n][(lg << 2) + i];
        #pragma unroll
        for (int i = 0; i < 4; ++i)
            #pragma unroll
            for (int j = 0; j < 4; ++j) acc2[i][j] = fmaf(a[i], bb[j], acc2[i][j]);
    }
    float Dh = Dp[h];
    #pragma unroll
    for (int i = 0; i < 4; ++i) {
        int l = (lg << 2) + i;
        int row = b * LSEQ + c * CHUNKx + l;
        float eA = ea[l];
        u16* yrow = xb + (size_t)row * LDX + h * HEADDIMx;
        #pragma unroll
        for (int j = 0; j < 4; ++j) {
            int p = (pg << 2) + j;
            float xsv = b2f(yrow[p]);
            yrow[p] = f2b(acc[i][j] + eA * acc2[i][j] + Dh * xsv);
        }
    }
}

// ---------- gated RMSNorm in place over y ----------
__global__ __launch_bounds__(256) void rmsgate_k(u16* __restrict__ xb,
                                                 const u16* __restrict__ zb,
                                                 const float* __restrict__ w) {
    int row = blockIdx.x;
    const u16* zp = zb + (size_t)row * D_INNERx;
    u16* yp = xb + (size_t)row * LDX;
    float vals[8];
    float ss = 0.f;
    #pragma unroll
    for (int i = 0; i < 8; ++i) {
        int c = threadIdx.x + i * 256;
        float z = b2f(zp[c]);
        float y = b2f(yp[c]) * silu_f(z);
        vals[i] = y; ss += y * y;
    }
    float tot = block_sum(ss);
    float scale = rsqrtf(tot * (1.f / D_INNERx) + 1e-5f);
    #pragma unroll
    for (int i = 0; i < 8; ++i) {
        int c = threadIdx.x + i * 256;
        yp[c] = f2b(vals[i] * scale * w[c]);
    }
}

// ---------- hidden = out[:, -1, :] ----------
__global__ void hidden_k(float* __restrict__ out) {
    int i = blockIdx.x * blockDim.x + threadIdx.x;
    int b = i >> 10, d = i & 1023;
    out[(size_t)NTOK * D_MODELx + i] = out[((size_t)(b * LSEQ + LSEQ - 1)) * D_MODELx + d];
}

extern "C" void kernel_launch(void* const* d_in, const int* in_sizes, int n_in,
                              void* d_out, int out_size, void* d_ws, size_t ws_size,
                              hipStream_t stream) {
    const float* x       = (const float*)d_in[0];
    const float* Wi      = (const float*)d_in[1];
    const float* bi      = (const float*)d_in[2];
    const float* ln_g    = (const float*)d_in[3];
    const float* ln_b    = (const float*)d_in[4];
    const float* Win     = (const float*)d_in[5];
    const float* conv_w  = (const float*)d_in[6];
    const float* conv_b  = (const float*)d_in[7];
    const float* dt_bias = (const float*)d_in[8];
    const float* A_log   = (const float*)d_in[9];
    const float* Dv      = (const float*)d_in[10];
    const float* rms_w   = (const float*)d_in[11];
    const float* Wout    = (const float*)d_in[12];
    float* out = (float*)d_out;

    // ws layout (118,489,088 B total — same bound as round 2):
    //   xb   [NTOK][LDX] bf16                         76,546,048
    //   ub   [NTOK][1024] bf16 / states fp32 / Woutb  33,554,432
    //   R    Wib+Winb early; G+acs+dtv late            8,388,608
    if (ws_size < 118489088ull) return;
    u16* xb  = (u16*)d_ws;
    u16* ub  = xb + (size_t)NTOK * LDX;
    float* states = (float*)ub;
    u16* Woutb = ub;                                   // after SSD (states dead)
    u16* Rb  = ub + (size_t)NTOK * D_MODELx;
    u16* Wib  = Rb;                                    // 1024x1024 bf16
    u16* Winb = Rb + (size_t)1024 * 1024;              // up to 2432x1024 bf16 (padded)
    float* G   = (float*)Rb;                           // overlays Wib/Winb after they die
    float* acs = G + (size_t)B_N * NCHUNKx * CHUNKx * CHUNKx;
    float* dtv = acs + (size_t)B_N * NHEADSx * NCHUNKx * CHUNKx;
    u16* xbf = xb;                                     // x bf16 overlay (dead before 3b)
    u16* zb  = (u16*)d_out;                            // z, dead before final GEMM

    // 0a. x -> bf16 (into xb region)
    cvt_f2b_k<<<16384, 256, 0, stream>>>(x, xbf, 16777216 / 4);
    // 0b. Wi -> bf16
    cvt_f2b_k<<<1024, 256, 0, stream>>>(Wi, Wib, 1048576 / 4);
    // 1. u = x @ Wi^T + bi
    gemm_mfma<1><<<dim3(8, 128), 256, 0, stream>>>(
        xbf, Wib, bi, ub, NTOK, D_MODELx, D_INx, D_INx, D_MODELx);
    // 2. LayerNorm in place
    layernorm_k<<<NTOK, 256, 0, stream>>>(ub, ln_g, ln_b);
    // 3a. z = u @ Win[0:2048]^T -> d_out
    cvt_f2b_k<<<2048, 256, 0, stream>>>(Win, Winb, (2048 * 1024) / 4);
    gemm_mfma<1><<<dim3(16, 128), 256, 0, stream>>>(
        ub, Winb, nullptr, zb, NTOK, D_INNERx, D_MODELx, D_MODELx, D_INNERx);
    // 3b. xBCdt = u @ Win[2048:4384]^T -> xb  (N=2336 ragged; Winb padded to 2432 rows)
    cvt_f2b_k<<<2336, 256, 0, stream>>>(Win + (size_t)2048 * 1024, Winb, (2336 * 1024) / 4);
    gemm_mfma<1><<<dim3(19, 128), 256, 0, stream>>>(
        ub, Winb, nullptr, xb, NTOK, LDX, D_MODELx, D_MODELx, LDX);
    // 4. dt + per-chunk cumsum of A*dt
    dt_acs_k<<<(B_N * NHEADSx * NCHUNKx + 255) / 256, 256, 0, stream>>>(
        xb, dt_bias, A_log, dtv, acs);
    // 5. conv + silu in place
    conv_k<<<dim3(CONV_DIMx / 32, B_N), 256, 0, stream>>>(xb, conv_w, conv_b);
    // 6. G scores
    gscore_k<<<B_N * NCHUNKx, 256, 0, stream>>>(xb, G);
    // 7. SSD per batch
    for (int b = 0; b < B_N; ++b) {
        states_k<<<dim3(NCHUNKx, NHEADSx), 256, 0, stream>>>(xb, dtv, acs, states, b);
        scan_k<<<dim3(HEADDIMx * D_STATEx / 256, NHEADSx), 256, 0, stream>>>(acs, states, b);
        yout_k<<<dim3(NCHUNKx, NHEADSx), 256, 0, stream>>>(xb, dtv, acs, G, states, Dv, b);
    }
    // 8. gated RMSNorm in place over y
    rmsgate_k<<<NTOK, 256, 0, stream>>>(xb, zb, rms_w);
    // 9. Wout -> bf16 (states region dead), then out = yn @ Wout^T
    cvt_f2b_k<<<2048, 256, 0, stream>>>(Wout, Woutb, (2048 * 1024) / 4);
    gemm_mfma<0><<<dim3(8, 128), 256, 0, stream>>>(
        xb, Woutb, nullptr, out, NTOK, D_MODELx, D_INNERx, LDX, D_MODELx);
    // 10. hidden
    hidden_k<<<(B_N * D_MODELx) / 256, 256, 0, stream>>>(out);
}

// Round 4
// 697.717 us; speedup vs baseline: 6.0622x; 1.9632x over previous
//
#include <hip/hip_runtime.h>
#include <math.h>

typedef unsigned short u16;
typedef __attribute__((ext_vector_type(8))) short bf16x8;
typedef __attribute__((ext_vector_type(4))) float f32x4;

#define B_N 8
#define LSEQ 2048
#define D_INx 1024
#define D_MODELx 1024
#define D_STATEx 128
#define D_INNERx 2048
#define NHEADSx 32
#define HEADDIMx 64
#define CONV_DIMx 2304
#define D_IN_PROJx 4384
#define CHUNKx 64
#define NCHUNKx 32
#define NTOK (B_N*LSEQ)   // 16384

#define LDX 2336
#define XB_B 2048
#define XB_C 2176
#define XB_DT 2304

// ---------- bf16 helpers (storage only; math fp32) ----------
__device__ __forceinline__ float b2f(u16 u) {
    return __uint_as_float(((unsigned)u) << 16);
}
__device__ __forceinline__ u16 f2b(float f) {
    unsigned u = __float_as_uint(f);
    return (u16)((u + 0x7FFFu + ((u >> 16) & 1u)) >> 16);  // RNE
}

__device__ __forceinline__ float block_sum(float v) {
    __shared__ float sm[8];
    int lane = threadIdx.x & 63, wid = threadIdx.x >> 6;
    #pragma unroll
    for (int o = 32; o; o >>= 1) v += __shfl_xor(v, o);
    __syncthreads();
    if (lane == 0) sm[wid] = v;
    __syncthreads();
    float r = 0.f;
    int nw = blockDim.x >> 6;
    for (int w = 0; w < nw; ++w) r += sm[w];
    return r;
}

__device__ __forceinline__ float silu_f(float x) {
    return x / (1.f + expf(-x));
}

// ---------- fp32 -> bf16 conversion ----------
__global__ __launch_bounds__(256) void cvt_f2b_k(const float* __restrict__ in,
                                                 u16* __restrict__ out, int n4) {
    int i = blockIdx.x * 256 + threadIdx.x;
    if (i >= n4) return;
    float4 v = ((const float4*)in)[i];
    ushort4 o;
    o.x = f2b(v.x); o.y = f2b(v.y); o.z = f2b(v.z); o.w = f2b(v.w);
    ((ushort4*)out)[i] = o;
}

// ---------- bf16 MFMA GEMM (m97 structure, verified round 3) ----------
template<int CBF>
__global__ __launch_bounds__(256) void gemm_mfma(const u16* __restrict__ A,
                                                 const u16* __restrict__ W,
                                                 const float* __restrict__ bias,
                                                 void* __restrict__ Cv,
                                                 int M, int N, int K, int lda, int ldc) {
    __shared__ u16 As[128 * 32];
    __shared__ u16 Bs[128 * 32];

    int nwgx = gridDim.x;
    int nwg = nwgx * gridDim.y;
    int bid = blockIdx.y * nwgx + blockIdx.x;
    int cpx = nwg >> 3;
    bid = (bid & 7) * cpx + (bid >> 3);
    int bm = (bid / nwgx) * 128;
    int bn = (bid % nwgx) * 128;

    int tid = threadIdx.x, wid = tid >> 6, lane = tid & 63;
    int lr = lane & 15, lk = (lane >> 4) << 3;
    int wr = (wid >> 1) << 6, wc = (wid & 1) << 6;

    const u16* srcp[4];
    u16* ldsp[4];
    #pragma unroll
    for (int cc = 0; cc < 4; ++cc) {
        int ch = wid * 4 + cc;
        int r = lane >> 2, col8 = (lane & 3) << 3;
        if (ch < 8) {
            srcp[cc] = A + (size_t)(bm + ch * 16 + r) * lda + col8;
            ldsp[cc] = &As[ch * 512];
        } else {
            srcp[cc] = W + (size_t)(bn + (ch - 8) * 16 + r) * K + col8;
            ldsp[cc] = &Bs[(ch - 8) * 512];
        }
    }

    f32x4 acc[4][4];
    #pragma unroll
    for (int m = 0; m < 4; ++m)
        #pragma unroll
        for (int n = 0; n < 4; ++n)
            acc[m][n] = (f32x4){0.f, 0.f, 0.f, 0.f};

    for (int k0 = 0; k0 < K; k0 += 32) {
        #pragma unroll
        for (int cc = 0; cc < 4; ++cc)
            __builtin_amdgcn_global_load_lds(
                (const __attribute__((address_space(1))) void*)(srcp[cc] + k0),
                (__attribute__((address_space(3))) void*)ldsp[cc], 16, 0, 0);
        __syncthreads();
        bf16x8 af[4], bfr[4];
        #pragma unroll
        for (int m = 0; m < 4; ++m)
            af[m] = *(bf16x8*)&As[(wr + m * 16 + lr) * 32 + lk];
        #pragma unroll
        for (int n = 0; n < 4; ++n)
            bfr[n] = *(bf16x8*)&Bs[(wc + n * 16 + lr) * 32 + lk];
        #pragma unroll
        for (int m = 0; m < 4; ++m)
            #pragma unroll
            for (int n = 0; n < 4; ++n)
                acc[m][n] = __builtin_amdgcn_mfma_f32_16x16x32_bf16(af[m], bfr[n], acc[m][n], 0, 0, 0);
        __syncthreads();
    }

    int crow = bm + wr + ((lane >> 4) << 2);
    int ccol = bn + wc + (lane & 15);
    #pragma unroll
    for (int n = 0; n < 4; ++n) {
        int col = ccol + n * 16;
        if (col < N) {
            float bv = bias ? bias[col] : 0.f;
            #pragma unroll
            for (int m = 0; m < 4; ++m) {
                #pragma unroll
                for (int j = 0; j < 4; ++j) {
                    int row = crow + m * 16 + j;
                    float v = acc[m][n][j] + bv;
                    if constexpr (CBF) ((u16*)Cv)[(size_t)row * ldc + col] = f2b(v);
                    else               ((float*)Cv)[(size_t)row * ldc + col] = v;
                }
            }
        }
    }
}

// ---------- LayerNorm (in place on bf16 u) ----------
__global__ __launch_bounds__(256) void layernorm_k(u16* __restrict__ u,
                                                   const float* __restrict__ g,
                                                   const float* __restrict__ bt) {
    int row = blockIdx.x;
    u16* p = u + (size_t)row * D_MODELx;
    float v[4]; float s = 0.f;
    #pragma unroll
    for (int i = 0; i < 4; ++i) { v[i] = b2f(p[threadIdx.x + i * 256]); s += v[i]; }
    float mean = block_sum(s) * (1.f / D_MODELx);
    float vs = 0.f;
    #pragma unroll
    for (int i = 0; i < 4; ++i) { float d = v[i] - mean; vs += d * d; }
    float var = block_sum(vs) * (1.f / D_MODELx);
    float inv = rsqrtf(var + 1e-5f);
    #pragma unroll
    for (int i = 0; i < 4; ++i) {
        int c = threadIdx.x + i * 256;
        p[c] = f2b((v[i] - mean) * inv * g[c] + bt[c]);
    }
}

// ---------- dt softplus + per-chunk cumsum: one wave per (b,h,c) ----------
__global__ __launch_bounds__(256) void dt_acs_k(const u16* __restrict__ xb,
                                                const float* __restrict__ dt_bias,
                                                const float* __restrict__ A_log,
                                                float* __restrict__ dtv, float* __restrict__ acs) {
    int gid = blockIdx.x * 4 + (threadIdx.x >> 6);
    int lane = threadIdx.x & 63;
    int c = gid & 31;
    int h = (gid >> 5) & 31;
    int b = gid >> 10;
    float A = -expf(A_log[h]);
    int row = b * LSEQ + c * CHUNKx + lane;
    float x = b2f(xb[(size_t)row * LDX + XB_DT + h]) + dt_bias[h];
    float d = (x > 20.f) ? x : log1pf(expf(x));
    dtv[(size_t)row * NHEADSx + h] = d;
    float v = A * d;
    #pragma unroll
    for (int off = 1; off < 64; off <<= 1) {
        float t = __shfl_up(v, off);
        if (lane >= off) v += t;
    }
    acs[(((size_t)(b * NHEADSx + h)) * NCHUNKx + c) * CHUNKx + lane] = v;
}

// ---------- causal depthwise conv (k=4) + SiLU, in place ----------
__global__ __launch_bounds__(256) void conv_k(u16* __restrict__ xb,
                                              const float* __restrict__ w,
                                              const float* __restrict__ bias) {
    int chl = threadIdx.x & 31, seg = threadIdx.x >> 5;
    int ch = blockIdx.x * 32 + chl;
    int b = blockIdx.y;
    float w0 = w[ch * 4 + 0], w1 = w[ch * 4 + 1], w2 = w[ch * 4 + 2], w3 = w[ch * 4 + 3];
    float bs = bias[ch];
    size_t base = ((size_t)b * LSEQ + seg * 256) * LDX + ch;
    float h0 = 0.f, h1 = 0.f, h2 = 0.f;
    if (seg) {
        h0 = b2f(xb[base - 3 * (size_t)LDX]);
        h1 = b2f(xb[base - 2 * (size_t)LDX]);
        h2 = b2f(xb[base - 1 * (size_t)LDX]);
    }
    __syncthreads();
    for (int i = 0; i < 256; ++i) {
        float xl = b2f(xb[base + (size_t)i * LDX]);
        float o = fmaf(w3, xl, fmaf(w2, h2, fmaf(w1, h1, fmaf(w0, h0, bs))));
        xb[base + (size_t)i * LDX] = f2b(silu_f(o));
        h0 = h1; h1 = h2; h2 = xl;
    }
}

// ---------- fused SSD: G + Y_diag + Y_off + state scan, MFMA, one (b,h) per block ----------
__device__ __forceinline__ bf16x8 scale_frag(bf16x8 v, const float* s) {
    bf16x8 r;
    #pragma unroll
    for (int j = 0; j < 8; ++j) {
        float f = b2f((u16)v[j]) * s[j];
        r[j] = (short)f2b(f);
    }
    return r;
}

__global__ __launch_bounds__(512) void ssd_k(u16* __restrict__ xb,
                                             const float* __restrict__ dtv,
                                             const float* __restrict__ acs,
                                             const float* __restrict__ Dp) {
    // LDS tiles (row pads keep 16B alignment + 2 lanes/bank reads)
    __shared__ u16 Xs[64 * 72];    // xs  [l][p]
    __shared__ u16 Xt[64 * 72];    // xs^T [p][l]
    __shared__ u16 Bl[64 * 136];   // B   [s][n]
    __shared__ u16 Bt[128 * 72];   // B^T [n][l]
    __shared__ u16 Cl[64 * 136];   // C   [l][n]
    __shared__ u16 Gp[64 * 72];    // masked G [l][s]
    __shared__ u16 Sp[64 * 136];   // prefix state S [p][n] (bf16 mirror)
    __shared__ float acss[64], eaS[64], ddS[64], dtS[64];
    __shared__ float decchunkS;

    int h = blockIdx.x, b = blockIdx.y;
    int tid = threadIdx.x;
    int w = tid >> 6, lane = tid & 63, l15 = lane & 15, g = lane >> 4;
    int lt = w >> 1, hf = w & 1;
    float Dh = Dp[h];

    // staging thread mapping
    int sr = tid >> 3, scq = tid & 7;        // load/write: row 0..63, col-chunk 0..7
    int bl = tid & 63, bq = tid >> 6;        // build: row 0..63, 8-col group 0..7

    // running state S^T[n][p]: wave w owns n-rows 16w..16w+15 x 4 p-tiles
    f32x4 sreg[4];
    #pragma unroll
    for (int pt = 0; pt < 4; ++pt) sreg[pt] = (f32x4){0.f, 0.f, 0.f, 0.f};

    for (int i = tid; i < 64 * 136; i += 512) Sp[i] = 0;

    // ---- prologue: stage chunk 0 ----
    {
        size_t rowb = ((size_t)(b * LSEQ) + sr) * LDX;
        uint4 rXs = *(const uint4*)(xb + rowb + h * 64 + scq * 8);
        uint4 rB0 = *(const uint4*)(xb + rowb + XB_B + scq * 8);
        uint4 rB1 = *(const uint4*)(xb + rowb + XB_B + 64 + scq * 8);
        uint4 rC0 = *(const uint4*)(xb + rowb + XB_C + scq * 8);
        uint4 rC1 = *(const uint4*)(xb + rowb + XB_C + 64 + scq * 8);
        *(uint4*)&Xs[sr * 72 + scq * 8] = rXs;
        *(uint4*)&Bl[sr * 136 + scq * 8] = rB0;
        *(uint4*)&Bl[sr * 136 + 64 + scq * 8] = rB1;
        *(uint4*)&Cl[sr * 136 + scq * 8] = rC0;
        *(uint4*)&Cl[sr * 136 + 64 + scq * 8] = rC1;
    }
    __syncthreads();
    {
        bf16x8 vx = *(bf16x8*)&Xs[bl * 72 + bq * 8];
        bf16x8 v0 = *(bf16x8*)&Bl[bl * 136 + bq * 8];
        bf16x8 v1 = *(bf16x8*)&Bl[bl * 136 + 64 + bq * 8];
        #pragma unroll
        for (int j = 0; j < 8; ++j) {
            Xt[(bq * 8 + j) * 72 + bl] = (u16)vx[j];
            Bt[(bq * 8 + j) * 72 + bl] = (u16)v0[j];
            Bt[(64 + bq * 8 + j) * 72 + bl] = (u16)v1[j];
        }
    }

    for (int c = 0; c < NCHUNKx; ++c) {
        int row0 = b * LSEQ + c * CHUNKx;
        // (a) issue next-chunk global loads
        uint4 rXs, rB0, rB1, rC0, rC1;
        if (c + 1 < NCHUNKx) {
            size_t rowb = ((size_t)row0 + 64 + sr) * LDX;
            rXs = *(const uint4*)(xb + rowb + h * 64 + scq * 8);
            rB0 = *(const uint4*)(xb + rowb + XB_B + scq * 8);
            rB1 = *(const uint4*)(xb + rowb + XB_B + 64 + scq * 8);
            rC0 = *(const uint4*)(xb + rowb + XB_C + scq * 8);
            rC1 = *(const uint4*)(xb + rowb + XB_C + 64 + scq * 8);
        }
        // (b) per-chunk scalars
        if (tid < 64) {
            int l = tid;
            float a = acs[(((size_t)(b * NHEADSx + h)) * NCHUNKx + c) * CHUNKx + l];
            float a63 = __shfl(a, 63);
            float d = dtv[(size_t)(row0 + l) * NHEADSx + h];
            acss[l] = a;
            eaS[l] = expf(a);
            dtS[l] = d;
            ddS[l] = d * expf(a63 - a);
            if (l == 0) decchunkS = expf(a63);
        }
        __syncthreads();

        // (c) G = C @ B^T  (fp32 acc), mask+decay, write bf16 Gp
        f32x4 accG[2];
        accG[0] = (f32x4){0.f, 0.f, 0.f, 0.f};
        accG[1] = (f32x4){0.f, 0.f, 0.f, 0.f};
        #pragma unroll
        for (int kk = 0; kk < 4; ++kk) {
            bf16x8 aC = *(bf16x8*)&Cl[(16 * lt + l15) * 136 + 32 * kk + 8 * g];
            #pragma unroll
            for (int q = 0; q < 2; ++q) {
                int st = 2 * hf + q;
                bf16x8 bB = *(bf16x8*)&Bl[(16 * st + l15) * 136 + 32 * kk + 8 * g];
                accG[q] = __builtin_amdgcn_mfma_f32_16x16x32_bf16(aC, bB, accG[q], 0, 0, 0);
            }
        }
        float dc = decchunkS;
        #pragma unroll
        for (int q = 0; q < 2; ++q) {
            int s = 16 * (2 * hf + q) + l15;
            float as = acss[s];
            #pragma unroll
            for (int j = 0; j < 4; ++j) {
                int l = 16 * lt + 4 * g + j;
                float v = (s <= l) ? accG[q][j] * expf(acss[l] - as) : 0.f;
                Gp[l * 72 + s] = f2b(v);
            }
        }
        // prescale running state by exp(acs_last)
        #pragma unroll
        for (int pt = 0; pt < 4; ++pt)
            #pragma unroll
            for (int j = 0; j < 4; ++j)
                sreg[pt][j] *= dc;
        __syncthreads();

        // (d) Y = (C@S^T)*ea + (L.G)@xd + D*xs ; SB^T accumulate into sreg
        f32x4 yac[2];
        yac[0] = (f32x4){0.f, 0.f, 0.f, 0.f};
        yac[1] = (f32x4){0.f, 0.f, 0.f, 0.f};
        #pragma unroll
        for (int kk = 0; kk < 4; ++kk) {
            bf16x8 aC = *(bf16x8*)&Cl[(16 * lt + l15) * 136 + 32 * kk + 8 * g];
            #pragma unroll
            for (int q = 0; q < 2; ++q) {
                int pt = 2 * hf + q;
                bf16x8 bS = *(bf16x8*)&Sp[(16 * pt + l15) * 136 + 32 * kk + 8 * g];
                yac[q] = __builtin_amdgcn_mfma_f32_16x16x32_bf16(aC, bS, yac[q], 0, 0, 0);
            }
        }
        #pragma unroll
        for (int q = 0; q < 2; ++q)
            #pragma unroll
            for (int j = 0; j < 4; ++j)
                yac[q][j] *= eaS[16 * lt + 4 * g + j];
        #pragma unroll
        for (int kk = 0; kk < 2; ++kk) {
            bf16x8 aG = *(bf16x8*)&Gp[(16 * lt + l15) * 72 + 32 * kk + 8 * g];
            #pragma unroll
            for (int q = 0; q < 2; ++q) {
                int pt = 2 * hf + q;
                bf16x8 bX = *(bf16x8*)&Xt[(16 * pt + l15) * 72 + 32 * kk + 8 * g];
                bX = scale_frag(bX, &dtS[32 * kk + 8 * g]);
                yac[q] = __builtin_amdgcn_mfma_f32_16x16x32_bf16(aG, bX, yac[q], 0, 0, 0);
            }
        }
        #pragma unroll
        for (int kk = 0; kk < 2; ++kk) {
            bf16x8 aB = *(bf16x8*)&Bt[(16 * w + l15) * 72 + 32 * kk + 8 * g];
            #pragma unroll
            for (int pt = 0; pt < 4; ++pt) {
                bf16x8 bX = *(bf16x8*)&Xt[(16 * pt + l15) * 72 + 32 * kk + 8 * g];
                bX = scale_frag(bX, &ddS[32 * kk + 8 * g]);
                sreg[pt] = __builtin_amdgcn_mfma_f32_16x16x32_bf16(aB, bX, sreg[pt], 0, 0, 0);
            }
        }
        // epilogue: y = yac + D*xs -> global (over xs columns)
        #pragma unroll
        for (int q = 0; q < 2; ++q) {
            int p = 16 * (2 * hf + q) + l15;
            #pragma unroll
            for (int j = 0; j < 4; ++j) {
                int l = 16 * lt + 4 * g + j;
                float v = yac[q][j] + Dh * b2f(Xs[l * 72 + p]);
                xb[(size_t)(row0 + l) * LDX + h * 64 + p] = f2b(v);
            }
        }
        __syncthreads();

        // (e) write S -> Sp (bf16) for next chunk; stage next tiles
        #pragma unroll
        for (int pt = 0; pt < 4; ++pt) {
            ushort4 pk;
            pk.x = f2b(sreg[pt][0]); pk.y = f2b(sreg[pt][1]);
            pk.z = f2b(sreg[pt][2]); pk.w = f2b(sreg[pt][3]);
            *(ushort4*)&Sp[(16 * pt + l15) * 136 + 16 * w + 4 * g] = pk;
        }
        if (c + 1 < NCHUNKx) {
            *(uint4*)&Xs[sr * 72 + scq * 8] = rXs;
            *(uint4*)&Bl[sr * 136 + scq * 8] = rB0;
            *(uint4*)&Bl[sr * 136 + 64 + scq * 8] = rB1;
            *(uint4*)&Cl[sr * 136 + scq * 8] = rC0;
            *(uint4*)&Cl[sr * 136 + 64 + scq * 8] = rC1;
        }
        __syncthreads();
        if (c + 1 < NCHUNKx) {
            bf16x8 vx = *(bf16x8*)&Xs[bl * 72 + bq * 8];
            bf16x8 v0 = *(bf16x8*)&Bl[bl * 136 + bq * 8];
            bf16x8 v1 = *(bf16x8*)&Bl[bl * 136 + 64 + bq * 8];
            #pragma unroll
            for (int j = 0; j < 8; ++j) {
                Xt[(bq * 8 + j) * 72 + bl] = (u16)vx[j];
                Bt[(bq * 8 + j) * 72 + bl] = (u16)v0[j];
                Bt[(64 + bq * 8 + j) * 72 + bl] = (u16)v1[j];
            }
        }
    }
}

// ---------- gated RMSNorm in place over y ----------
__global__ __launch_bounds__(256) void rmsgate_k(u16* __restrict__ xb,
                                                 const u16* __restrict__ zb,
                                                 const float* __restrict__ w) {
    int row = blockIdx.x;
    const u16* zp = zb + (size_t)row * D_INNERx;
    u16* yp = xb + (size_t)row * LDX;
    float vals[8];
    float ss = 0.f;
    #pragma unroll
    for (int i = 0; i < 8; ++i) {
        int c = threadIdx.x + i * 256;
        float z = b2f(zp[c]);
        float y = b2f(yp[c]) * silu_f(z);
        vals[i] = y; ss += y * y;
    }
    float tot = block_sum(ss);
    float scale = rsqrtf(tot * (1.f / D_INNERx) + 1e-5f);
    #pragma unroll
    for (int i = 0; i < 8; ++i) {
        int c = threadIdx.x + i * 256;
        yp[c] = f2b(vals[i] * scale * w[c]);
    }
}

// ---------- hidden = out[:, -1, :] ----------
__global__ void hidden_k(float* __restrict__ out) {
    int i = blockIdx.x * blockDim.x + threadIdx.x;
    int b = i >> 10, d = i & 1023;
    out[(size_t)NTOK * D_MODELx + i] = out[((size_t)(b * LSEQ + LSEQ - 1)) * D_MODELx + d];
}

extern "C" void kernel_launch(void* const* d_in, const int* in_sizes, int n_in,
                              void* d_out, int out_size, void* d_ws, size_t ws_size,
                              hipStream_t stream) {
    const float* x       = (const float*)d_in[0];
    const float* Wi      = (const float*)d_in[1];
    const float* bi      = (const float*)d_in[2];
    const float* ln_g    = (const float*)d_in[3];
    const float* ln_b    = (const float*)d_in[4];
    const float* Win     = (const float*)d_in[5];
    const float* conv_w  = (const float*)d_in[6];
    const float* conv_b  = (const float*)d_in[7];
    const float* dt_bias = (const float*)d_in[8];
    const float* A_log   = (const float*)d_in[9];
    const float* Dv      = (const float*)d_in[10];
    const float* rms_w   = (const float*)d_in[11];
    const float* Wout    = (const float*)d_in[12];
    float* out = (float*)d_out;

    if (ws_size < 118489088ull) return;
    u16* xb  = (u16*)d_ws;                                   // [NTOK][LDX] bf16
    u16* ub  = xb + (size_t)NTOK * LDX;                      // [NTOK][1024] bf16
    u16* Woutb = ub;                                         // overlay after y ready
    u16* Rb  = ub + (size_t)NTOK * D_MODELx;
    u16* Wib  = Rb;
    u16* Winb = Rb + (size_t)1024 * 1024;
    float* acs = (float*)Rb;                                 // overlays Wib/Winb after GEMMs
    float* dtv = acs + (size_t)B_N * NHEADSx * NCHUNKx * CHUNKx;
    u16* xbf = xb;
    u16* zb  = (u16*)d_out;

    // 0. conversions
    cvt_f2b_k<<<16384, 256, 0, stream>>>(x, xbf, 16777216 / 4);
    cvt_f2b_k<<<1024, 256, 0, stream>>>(Wi, Wib, 1048576 / 4);
    // 1. u = x @ Wi^T + bi
    gemm_mfma<1><<<dim3(8, 128), 256, 0, stream>>>(
        xbf, Wib, bi, ub, NTOK, D_MODELx, D_INx, D_INx, D_MODELx);
    // 2. LayerNorm
    layernorm_k<<<NTOK, 256, 0, stream>>>(ub, ln_g, ln_b);
    // 3a. z = u @ Win[0:2048]^T -> d_out
    cvt_f2b_k<<<2048, 256, 0, stream>>>(Win, Winb, (2048 * 1024) / 4);
    gemm_mfma<1><<<dim3(16, 128), 256, 0, stream>>>(
        ub, Winb, nullptr, zb, NTOK, D_INNERx, D_MODELx, D_MODELx, D_INNERx);
    // 3b. xBCdt = u @ Win[2048:4384]^T -> xb
    cvt_f2b_k<<<2336, 256, 0, stream>>>(Win + (size_t)2048 * 1024, Winb, (2336 * 1024) / 4);
    gemm_mfma<1><<<dim3(19, 128), 256, 0, stream>>>(
        ub, Winb, nullptr, xb, NTOK, LDX, D_MODELx, D_MODELx, LDX);
    // 4. dt + per-chunk cumsum (wave-parallel scan)
    dt_acs_k<<<2048, 256, 0, stream>>>(xb, dt_bias, A_log, dtv, acs);
    // 5. conv + silu in place
    conv_k<<<dim3(CONV_DIMx / 32, B_N), 256, 0, stream>>>(xb, conv_w, conv_b);
    // 6+7. fused SSD (G, states, scan, Y) -> y over xs columns
    ssd_k<<<dim3(NHEADSx, B_N), 512, 0, stream>>>(xb, dtv, acs, Dv);
    // 8. gated RMSNorm in place over y
    rmsgate_k<<<NTOK, 256, 0, stream>>>(xb, zb, rms_w);
    // 9. out = yn @ Wout^T
    cvt_f2b_k<<<2048, 256, 0, stream>>>(Wout, Woutb, (2048 * 1024) / 4);
    gemm_mfma<0><<<dim3(8, 128), 256, 0, stream>>>(
        xb, Woutb, nullptr, out, NTOK, D_MODELx, D_INNERx, LDX, D_MODELx);
    // 10. hidden
    hidden_k<<<(B_N * D_MODELx) / 256, 256, 0, stream>>>(out);
}